// Round 1
// baseline (1972.972 us; speedup 1.0000x reference)
//
#include <hip/hip_runtime.h>
#include <cstdint>

// Problem constants (MultiHeadAttention w/ sparsemax, B=2, S=2048, D=1024, H=16)
#define B_SZ   2
#define S_LEN  2048
#define DMODEL 1024
#define NHEAD  16
#define DK     64
#define BHN    (B_SZ * NHEAD)            // 32
#define M_ROWS (B_SZ * S_LEN)            // 4096
#define HEAD_ELEMS ((size_t)BHN * S_LEN * DK)  // 4,194,304 floats (== M_ROWS*DMODEL)

// ---------------------------------------------------------------- wave reduce
__device__ __forceinline__ float wave_sum64(float v) {
    v += __shfl_xor(v, 32, 64);
    v += __shfl_xor(v, 16, 64);
    v += __shfl_xor(v, 8, 64);
    v += __shfl_xor(v, 4, 64);
    v += __shfl_xor(v, 2, 64);
    v += __shfl_xor(v, 1, 64);
    return v;
}
__device__ __forceinline__ float wave_max64(float v) {
    v = fmaxf(v, __shfl_xor(v, 32, 64));
    v = fmaxf(v, __shfl_xor(v, 16, 64));
    v = fmaxf(v, __shfl_xor(v, 8, 64));
    v = fmaxf(v, __shfl_xor(v, 4, 64));
    v = fmaxf(v, __shfl_xor(v, 2, 64));
    v = fmaxf(v, __shfl_xor(v, 1, 64));
    return v;
}

// ------------------------------------------------------- QKV projection GEMMs
// C = A @ W^T + b, A[4096,1024], W[1024,1024] (both K-contiguous -> NT GEMM).
// Output scattered to head-major ws layout [B,H,S,DK].
__global__ __launch_bounds__(256)
void qkv_proj_kernel(const float* __restrict__ xq, const float* __restrict__ xk,
                     const float* __restrict__ xv,
                     const float* __restrict__ Wq, const float* __restrict__ bq,
                     const float* __restrict__ Wk, const float* __restrict__ bk,
                     const float* __restrict__ Wv, const float* __restrict__ bv,
                     float* __restrict__ ws_qkv) {
    const int which = blockIdx.z;
    const float* A    = (which == 0) ? xq : (which == 1) ? xk : xv;
    const float* W    = (which == 0) ? Wq : (which == 1) ? Wk : Wv;
    const float* bias = (which == 0) ? bq : (which == 1) ? bk : bv;
    float* dst = ws_qkv + (size_t)which * HEAD_ELEMS;

    const int row0 = blockIdx.x * 64;
    const int col0 = blockIdx.y * 64;

    __shared__ float As[64 * 17];
    __shared__ float Ws[64 * 17];

    const int tid = threadIdx.x;
    const int tx = tid & 15;
    const int ty = tid >> 4;
    const int lr = tid >> 2;          // load row 0..63
    const int lc = (tid & 3) << 2;    // load col {0,4,8,12}

    float acc[4][4];
#pragma unroll
    for (int i = 0; i < 4; ++i)
#pragma unroll
        for (int j = 0; j < 4; ++j)
            acc[i][j] = bias[col0 + tx * 4 + j];

    for (int k0 = 0; k0 < DMODEL; k0 += 16) {
        float4 av = *(const float4*)(A + (size_t)(row0 + lr) * DMODEL + k0 + lc);
        float4 wv = *(const float4*)(W + (size_t)(col0 + lr) * DMODEL + k0 + lc);
        __syncthreads();
        As[lr * 17 + lc + 0] = av.x; As[lr * 17 + lc + 1] = av.y;
        As[lr * 17 + lc + 2] = av.z; As[lr * 17 + lc + 3] = av.w;
        Ws[lr * 17 + lc + 0] = wv.x; Ws[lr * 17 + lc + 1] = wv.y;
        Ws[lr * 17 + lc + 2] = wv.z; Ws[lr * 17 + lc + 3] = wv.w;
        __syncthreads();
#pragma unroll
        for (int kk = 0; kk < 16; ++kk) {
            float a[4], w[4];
#pragma unroll
            for (int i = 0; i < 4; ++i) a[i] = As[(ty * 4 + i) * 17 + kk];
#pragma unroll
            for (int j = 0; j < 4; ++j) w[j] = Ws[(tx * 4 + j) * 17 + kk];
#pragma unroll
            for (int i = 0; i < 4; ++i)
#pragma unroll
                for (int j = 0; j < 4; ++j)
                    acc[i][j] += a[i] * w[j];
        }
    }

    // scatter to [B,H,S,DK]; col0 is a multiple of 64 so the head h is uniform.
    const int h = col0 >> 6;
#pragma unroll
    for (int i = 0; i < 4; ++i) {
        const int m = row0 + ty * 4 + i;
        const int b = m >> 11;
        const int s = m & 2047;
        float* drow = dst + (((size_t)(b * NHEAD + h)) * S_LEN + s) * DK;
#pragma unroll
        for (int j = 0; j < 4; ++j)
            drow[tx * 4 + j] = acc[i][j];
    }
}

// ------------------------------------------------------------- logits = QK^T/8
__global__ __launch_bounds__(256)
void logits_kernel(const float* __restrict__ ws_qkv, float* __restrict__ attn) {
    const int bh = blockIdx.z;
    const float* Qh = ws_qkv + (size_t)bh * (S_LEN * DK);
    const float* Kh = ws_qkv + HEAD_ELEMS + (size_t)bh * (S_LEN * DK);
    const int row0 = blockIdx.x * 64;
    const int col0 = blockIdx.y * 64;

    __shared__ float As[64 * 17];
    __shared__ float Ws[64 * 17];

    const int tid = threadIdx.x;
    const int tx = tid & 15;
    const int ty = tid >> 4;
    const int lr = tid >> 2;
    const int lc = (tid & 3) << 2;

    float acc[4][4] = {};

    for (int k0 = 0; k0 < DK; k0 += 16) {
        float4 av = *(const float4*)(Qh + (size_t)(row0 + lr) * DK + k0 + lc);
        float4 wv = *(const float4*)(Kh + (size_t)(col0 + lr) * DK + k0 + lc);
        __syncthreads();
        As[lr * 17 + lc + 0] = av.x; As[lr * 17 + lc + 1] = av.y;
        As[lr * 17 + lc + 2] = av.z; As[lr * 17 + lc + 3] = av.w;
        Ws[lr * 17 + lc + 0] = wv.x; Ws[lr * 17 + lc + 1] = wv.y;
        Ws[lr * 17 + lc + 2] = wv.z; Ws[lr * 17 + lc + 3] = wv.w;
        __syncthreads();
#pragma unroll
        for (int kk = 0; kk < 16; ++kk) {
            float a[4], w[4];
#pragma unroll
            for (int i = 0; i < 4; ++i) a[i] = As[(ty * 4 + i) * 17 + kk];
#pragma unroll
            for (int j = 0; j < 4; ++j) w[j] = Ws[(tx * 4 + j) * 17 + kk];
#pragma unroll
            for (int i = 0; i < 4; ++i)
#pragma unroll
                for (int j = 0; j < 4; ++j)
                    acc[i][j] += a[i] * w[j];
        }
    }

#pragma unroll
    for (int i = 0; i < 4; ++i) {
        float* arow = attn + ((size_t)bh * S_LEN + (row0 + ty * 4 + i)) * S_LEN + col0;
#pragma unroll
        for (int j = 0; j < 4; ++j)
            arow[tx * 4 + j] = acc[i][j] * 0.125f;  // 1/sqrt(64)
    }
}

// ---------------------------------------------------- sparsemax (in-place rows)
// One wave per row of 2048; row lives in 32 VGPRs/lane. tau found by bisection
// on f(tau)=sum(relu(z-tau))-1 (monotone, bracket [max-1, max]) + exact refine.
__global__ __launch_bounds__(256)
void sparsemax_kernel(float* __restrict__ attn) {
    const int wave = threadIdx.x >> 6;
    const int lane = threadIdx.x & 63;
    const size_t row = (size_t)blockIdx.x * 4 + wave;   // < 65536
    float4* rp = (float4*)(attn + row * S_LEN);

    float z[32];
#pragma unroll
    for (int r = 0; r < 8; ++r) {
        float4 v = rp[r * 64 + lane];
        z[4 * r + 0] = v.x; z[4 * r + 1] = v.y;
        z[4 * r + 2] = v.z; z[4 * r + 3] = v.w;
    }

    float m = z[0];
#pragma unroll
    for (int j = 1; j < 32; ++j) m = fmaxf(m, z[j]);
    m = wave_max64(m);

    float lo = m - 1.0f, hi = m;   // f(lo)>=1, f(hi)=0
    for (int it = 0; it < 26; ++it) {
        const float mid = 0.5f * (lo + hi);
        float s = 0.0f;
#pragma unroll
        for (int j = 0; j < 32; ++j) s += fmaxf(z[j] - mid, 0.0f);
        s = wave_sum64(s);
        if (s >= 1.0f) lo = mid; else hi = mid;   // s uniform -> no divergence
    }
    const float tau0 = 0.5f * (lo + hi);

    float ssum = 0.0f, cnt = 0.0f;
#pragma unroll
    for (int j = 0; j < 32; ++j) {
        if (z[j] > tau0) { ssum += z[j]; cnt += 1.0f; }
    }
    ssum = wave_sum64(ssum);
    cnt  = wave_sum64(cnt);
    const float tau = (ssum - 1.0f) / cnt;

#pragma unroll
    for (int r = 0; r < 8; ++r) {
        float4 v;
        v.x = fmaxf(z[4 * r + 0] - tau, 0.0f);
        v.y = fmaxf(z[4 * r + 1] - tau, 0.0f);
        v.z = fmaxf(z[4 * r + 2] - tau, 0.0f);
        v.w = fmaxf(z[4 * r + 3] - tau, 0.0f);
        rp[r * 64 + lane] = v;
    }
}

// -------------------------------------------------------- attn_out = attn @ V
// NN GEMM per (b,h): [2048,2048] @ [2048,64]; output to ws [B,S,DMODEL].
__global__ __launch_bounds__(256)
void pv_kernel(const float* __restrict__ attn, const float* __restrict__ ws_qkv,
               float* __restrict__ attn_out) {
    const int bh = blockIdx.z;
    const int b = bh >> 4;
    const int h = bh & 15;
    const float* A = attn + (size_t)bh * S_LEN * S_LEN;
    const float* V = ws_qkv + 2 * HEAD_ELEMS + (size_t)bh * (S_LEN * DK);
    const int row0 = blockIdx.x * 64;

    __shared__ float As[64 * 17];
    __shared__ float Vs[16 * 68];

    const int tid = threadIdx.x;
    const int tx = tid & 15;
    const int ty = tid >> 4;
    const int lr = tid >> 2;          // A loader: row 0..63
    const int lc = (tid & 3) << 2;    //           k {0,4,8,12}
    const int vr = tid >> 4;          // V loader: k 0..15
    const int vc = (tid & 15) << 2;   //           n {0..60}

    float acc[4][4] = {};

    for (int k0 = 0; k0 < S_LEN; k0 += 16) {
        float4 av = *(const float4*)(A + (size_t)(row0 + lr) * S_LEN + k0 + lc);
        float4 vv = *(const float4*)(V + (size_t)(k0 + vr) * DK + vc);
        __syncthreads();
        As[lr * 17 + lc + 0] = av.x; As[lr * 17 + lc + 1] = av.y;
        As[lr * 17 + lc + 2] = av.z; As[lr * 17 + lc + 3] = av.w;
        Vs[vr * 68 + vc + 0] = vv.x; Vs[vr * 68 + vc + 1] = vv.y;
        Vs[vr * 68 + vc + 2] = vv.z; Vs[vr * 68 + vc + 3] = vv.w;
        __syncthreads();
#pragma unroll
        for (int kk = 0; kk < 16; ++kk) {
            float a[4], w[4];
#pragma unroll
            for (int i = 0; i < 4; ++i) a[i] = As[(ty * 4 + i) * 17 + kk];
#pragma unroll
            for (int j = 0; j < 4; ++j) w[j] = Vs[kk * 68 + tx * 4 + j];
#pragma unroll
            for (int i = 0; i < 4; ++i)
#pragma unroll
                for (int j = 0; j < 4; ++j)
                    acc[i][j] += a[i] * w[j];
        }
    }

#pragma unroll
    for (int i = 0; i < 4; ++i) {
        const int srow = row0 + ty * 4 + i;
        float* orow = attn_out + ((size_t)(b * S_LEN + srow)) * DMODEL + h * 64;
#pragma unroll
        for (int j = 0; j < 4; ++j)
            orow[tx * 4 + j] = acc[i][j];
    }
}

// ------------------------------------------------------ output = X @ Wfc^T + b
__global__ __launch_bounds__(256)
void fc_kernel(const float* __restrict__ X, const float* __restrict__ Wfc,
               const float* __restrict__ bfc, float* __restrict__ out) {
    const int row0 = blockIdx.x * 64;
    const int col0 = blockIdx.y * 64;

    __shared__ float As[64 * 17];
    __shared__ float Ws[64 * 17];

    const int tid = threadIdx.x;
    const int tx = tid & 15;
    const int ty = tid >> 4;
    const int lr = tid >> 2;
    const int lc = (tid & 3) << 2;

    float acc[4][4];
#pragma unroll
    for (int i = 0; i < 4; ++i)
#pragma unroll
        for (int j = 0; j < 4; ++j)
            acc[i][j] = bfc[col0 + tx * 4 + j];

    for (int k0 = 0; k0 < DMODEL; k0 += 16) {
        float4 av = *(const float4*)(X + (size_t)(row0 + lr) * DMODEL + k0 + lc);
        float4 wv = *(const float4*)(Wfc + (size_t)(col0 + lr) * DMODEL + k0 + lc);
        __syncthreads();
        As[lr * 17 + lc + 0] = av.x; As[lr * 17 + lc + 1] = av.y;
        As[lr * 17 + lc + 2] = av.z; As[lr * 17 + lc + 3] = av.w;
        Ws[lr * 17 + lc + 0] = wv.x; Ws[lr * 17 + lc + 1] = wv.y;
        Ws[lr * 17 + lc + 2] = wv.z; Ws[lr * 17 + lc + 3] = wv.w;
        __syncthreads();
#pragma unroll
        for (int kk = 0; kk < 16; ++kk) {
            float a[4], w[4];
#pragma unroll
            for (int i = 0; i < 4; ++i) a[i] = As[(ty * 4 + i) * 17 + kk];
#pragma unroll
            for (int j = 0; j < 4; ++j) w[j] = Ws[(tx * 4 + j) * 17 + kk];
#pragma unroll
            for (int i = 0; i < 4; ++i)
#pragma unroll
                for (int j = 0; j < 4; ++j)
                    acc[i][j] += a[i] * w[j];
        }
    }

#pragma unroll
    for (int i = 0; i < 4; ++i) {
        float* orow = out + (size_t)(row0 + ty * 4 + i) * DMODEL + col0;
#pragma unroll
        for (int j = 0; j < 4; ++j)
            orow[tx * 4 + j] = acc[i][j];
    }
}

// ----------------------------------------------------------------------- launch
extern "C" void kernel_launch(void* const* d_in, const int* in_sizes, int n_in,
                              void* d_out, int out_size, void* d_ws, size_t ws_size,
                              hipStream_t stream) {
    const float* q   = (const float*)d_in[0];
    const float* k   = (const float*)d_in[1];
    const float* v   = (const float*)d_in[2];
    const float* Wq  = (const float*)d_in[3];
    const float* bq  = (const float*)d_in[4];
    const float* Wk  = (const float*)d_in[5];
    const float* bk  = (const float*)d_in[6];
    const float* Wv  = (const float*)d_in[7];
    const float* bv  = (const float*)d_in[8];
    const float* Wfc = (const float*)d_in[9];
    const float* bfc = (const float*)d_in[10];

    float* out  = (float*)d_out;                         // [B,S,DMODEL]
    float* attn = out + (size_t)M_ROWS * DMODEL;         // [B,H,S,S]

    // ws: Q,K,V head-major (3 * 16 MB) + attn_out (16 MB) = 64 MB
    float* ws_qkv   = (float*)d_ws;
    float* attn_out = ws_qkv + 3 * HEAD_ELEMS;

    qkv_proj_kernel<<<dim3(M_ROWS / 64, DMODEL / 64, 3), 256, 0, stream>>>(
        q, k, v, Wq, bq, Wk, bk, Wv, bv, ws_qkv);
    logits_kernel<<<dim3(S_LEN / 64, S_LEN / 64, BHN), 256, 0, stream>>>(ws_qkv, attn);
    sparsemax_kernel<<<dim3((BHN * S_LEN) / 4), 256, 0, stream>>>(attn);
    pv_kernel<<<dim3(S_LEN / 64, 1, BHN), 256, 0, stream>>>(attn, ws_qkv, attn_out);
    fc_kernel<<<dim3(M_ROWS / 64, DMODEL / 64), 256, 0, stream>>>(attn_out, Wfc, bfc, out);
}

// Round 2
// 1145.145 us; speedup vs baseline: 1.7229x; 1.7229x over previous
//
#include <hip/hip_runtime.h>
#include <hip/hip_bf16.h>
#include <cstdint>

// MultiHeadAttention w/ sparsemax: B=2, S=2048, D=1024, H=16, DK=64
#define S_LEN  2048
#define DMODEL 1024
#define NHEAD  16
#define M_ROWS 4096                       // B*S
#define HEAD_ELEMS (2048u * 64u)          // per (b,h) Q/K/V elems

typedef __attribute__((ext_vector_type(8))) short bf16x8;   // MFMA A/B frag (8 bf16)
typedef __attribute__((ext_vector_type(4))) float f32x4;    // MFMA C/D frag

__device__ __forceinline__ unsigned short f2bf(float f) {
    __hip_bfloat16 h = __float2bfloat16(f);
    return __builtin_bit_cast(unsigned short, h);
}

// ---------------------------------------------------------------- wave reduce
__device__ __forceinline__ float wave_sum64(float v) {
    v += __shfl_xor(v, 32, 64); v += __shfl_xor(v, 16, 64);
    v += __shfl_xor(v, 8, 64);  v += __shfl_xor(v, 4, 64);
    v += __shfl_xor(v, 2, 64);  v += __shfl_xor(v, 1, 64);
    return v;
}
__device__ __forceinline__ float wave_max64(float v) {
    v = fmaxf(v, __shfl_xor(v, 32, 64)); v = fmaxf(v, __shfl_xor(v, 16, 64));
    v = fmaxf(v, __shfl_xor(v, 8, 64));  v = fmaxf(v, __shfl_xor(v, 4, 64));
    v = fmaxf(v, __shfl_xor(v, 2, 64));  v = fmaxf(v, __shfl_xor(v, 1, 64));
    return v;
}

// --------------------------------------------------------------- cast fp32->bf16
// 16M elems: [0,4M)=xq [4M,8M)=xk [8M,12M)=xv [12M,13M)=Wq [13M,14M)=Wk
// [14M,15M)=Wv [15M,16M)=Wfc. Output contiguous bf16 at ws+0.
__global__ __launch_bounds__(256)
void cast_kernel(const float* __restrict__ xq, const float* __restrict__ xk,
                 const float* __restrict__ xv, const float* __restrict__ Wq,
                 const float* __restrict__ Wk, const float* __restrict__ Wv,
                 const float* __restrict__ Wfc, unsigned short* __restrict__ out) {
    const size_t e = ((size_t)blockIdx.x * 256 + threadIdx.x) * 4;
    const size_t M1 = 1u << 20, M4 = 4u << 20;
    const float* src; size_t off;
    if      (e < M4)        { src = xq;  off = e; }
    else if (e < 2 * M4)    { src = xk;  off = e - M4; }
    else if (e < 3 * M4)    { src = xv;  off = e - 2 * M4; }
    else if (e < 12*M1+M1)  { src = Wq;  off = e - 3 * M4; }
    else if (e < 14 * M1)   { src = Wk;  off = e - 13 * M1; }
    else if (e < 15 * M1)   { src = Wv;  off = e - 14 * M1; }
    else                    { src = Wfc; off = e - 15 * M1; }
    float4 v = *(const float4*)(src + off);
    unsigned int lo = ((unsigned)f2bf(v.y) << 16) | f2bf(v.x);
    unsigned int hi = ((unsigned)f2bf(v.w) << 16) | f2bf(v.z);
    uint2 st = { lo, hi };
    *(uint2*)(out + e) = st;
}

// ------------------------------------------------- qkv: C = A@W^T + b (bf16 MFMA)
// A[4096,1024] bf16, W[1024,1024] bf16 (NT). Output head-major bf16 [B,H,S,64].
__global__ __launch_bounds__(256)
void qkv_gemm(const unsigned short* __restrict__ x_bf,
              const unsigned short* __restrict__ W_bf,
              const float* __restrict__ bq, const float* __restrict__ bk,
              const float* __restrict__ bv,
              unsigned short* __restrict__ Q_bf, unsigned short* __restrict__ K_bf,
              unsigned short* __restrict__ V_bf) {
    const int which = blockIdx.z;
    const unsigned short* A = x_bf + (size_t)which * (4u << 20);
    const unsigned short* W = W_bf + (size_t)which * (1u << 20);
    const float* bias = (which == 0) ? bq : (which == 1) ? bk : bv;
    unsigned short* dst = (which == 0) ? Q_bf : (which == 1) ? K_bf : V_bf;

    const int row0 = blockIdx.x * 128;
    const int col0 = blockIdx.y * 128;

    __shared__ unsigned short As[128 * 40];   // stride 40 bf16 = 80 B (2-way free)
    __shared__ unsigned short Bs[128 * 40];

    const int t = threadIdx.x;
    const int wid = t >> 6, lane = t & 63;
    const int wm = wid >> 1, wn = wid & 1;
    const int l = lane & 15, quad = lane >> 4;

    const float bval = bias[col0 + wn * 64 + 0 * 16 + l];  // per-j below
    (void)bval;

    f32x4 acc[4][4];
#pragma unroll
    for (int i = 0; i < 4; ++i)
#pragma unroll
        for (int j = 0; j < 4; ++j) {
            float b_ = bias[col0 + wn * 64 + j * 16 + l];
            acc[i][j] = (f32x4){ b_, b_, b_, b_ };
        }

    for (int k0 = 0; k0 < DMODEL; k0 += 32) {
        uint4 ar[2], br[2];
#pragma unroll
        for (int i = 0; i < 2; ++i) {
            const int c = t + i * 256, r = c >> 2, q = (c & 3) * 8;
            ar[i] = *(const uint4*)(A + (size_t)(row0 + r) * DMODEL + k0 + q);
            br[i] = *(const uint4*)(W + (size_t)(col0 + r) * DMODEL + k0 + q);
        }
        __syncthreads();
#pragma unroll
        for (int i = 0; i < 2; ++i) {
            const int c = t + i * 256, r = c >> 2, q = (c & 3) * 8;
            *(uint4*)&As[r * 40 + q] = ar[i];
            *(uint4*)&Bs[r * 40 + q] = br[i];
        }
        __syncthreads();
        bf16x8 a[4], b[4];
#pragma unroll
        for (int i = 0; i < 4; ++i)
            a[i] = *(const bf16x8*)&As[(wm * 64 + i * 16 + l) * 40 + quad * 8];
#pragma unroll
        for (int j = 0; j < 4; ++j)
            b[j] = *(const bf16x8*)&Bs[(wn * 64 + j * 16 + l) * 40 + quad * 8];
#pragma unroll
        for (int i = 0; i < 4; ++i)
#pragma unroll
            for (int j = 0; j < 4; ++j)
                acc[i][j] = __builtin_amdgcn_mfma_f32_16x16x32_bf16(a[i], b[j], acc[i][j], 0, 0, 0);
    }

    // scatter bf16 to [B,H,S,64]
#pragma unroll
    for (int i = 0; i < 4; ++i)
#pragma unroll
        for (int r = 0; r < 4; ++r) {
            const int m = row0 + wm * 64 + i * 16 + quad * 4 + r;
            const int b_ = m >> 11, s = m & 2047;
#pragma unroll
            for (int j = 0; j < 4; ++j) {
                const int n = col0 + wn * 64 + j * 16 + l;
                const int h = n >> 6, d = n & 63;
                dst[(((size_t)(b_ * NHEAD + h)) * S_LEN + s) * 64 + d] = f2bf(acc[i][j][r]);
            }
        }
}

// --------------------------------------------- logits = Q@K^T / 8 (bf16 MFMA, K=64)
__global__ __launch_bounds__(256)
void logits_gemm(const unsigned short* __restrict__ Q_bf,
                 const unsigned short* __restrict__ K_bf,
                 float* __restrict__ attn) {
    const int bh = blockIdx.z;
    const unsigned short* Qh = Q_bf + (size_t)bh * HEAD_ELEMS;
    const unsigned short* Kh = K_bf + (size_t)bh * HEAD_ELEMS;
    const int row0 = blockIdx.x * 128;
    const int col0 = blockIdx.y * 128;

    __shared__ unsigned short As[128 * 72];   // stride 72 bf16 = 144 B
    __shared__ unsigned short Bs[128 * 72];

    const int t = threadIdx.x;
    const int wid = t >> 6, lane = t & 63;
    const int wm = wid >> 1, wn = wid & 1;
    const int l = lane & 15, quad = lane >> 4;

#pragma unroll
    for (int i = 0; i < 4; ++i) {
        const int c = t + i * 256, r = c >> 3, q = (c & 7) * 8;
        *(uint4*)&As[r * 72 + q] = *(const uint4*)(Qh + (size_t)(row0 + r) * 64 + q);
        *(uint4*)&Bs[r * 72 + q] = *(const uint4*)(Kh + (size_t)(col0 + r) * 64 + q);
    }
    __syncthreads();

    f32x4 acc[4][4] = {};
#pragma unroll
    for (int kk = 0; kk < 64; kk += 32) {
        bf16x8 a[4], b[4];
#pragma unroll
        for (int i = 0; i < 4; ++i)
            a[i] = *(const bf16x8*)&As[(wm * 64 + i * 16 + l) * 72 + kk + quad * 8];
#pragma unroll
        for (int j = 0; j < 4; ++j)
            b[j] = *(const bf16x8*)&Bs[(wn * 64 + j * 16 + l) * 72 + kk + quad * 8];
#pragma unroll
        for (int i = 0; i < 4; ++i)
#pragma unroll
            for (int j = 0; j < 4; ++j)
                acc[i][j] = __builtin_amdgcn_mfma_f32_16x16x32_bf16(a[i], b[j], acc[i][j], 0, 0, 0);
    }

    float* ap = attn + (size_t)bh * S_LEN * S_LEN;
#pragma unroll
    for (int i = 0; i < 4; ++i)
#pragma unroll
        for (int r = 0; r < 4; ++r) {
            const int m = row0 + wm * 64 + i * 16 + quad * 4 + r;
#pragma unroll
            for (int j = 0; j < 4; ++j) {
                const int n = col0 + wn * 64 + j * 16 + l;
                ap[(size_t)m * S_LEN + n] = acc[i][j][r] * 0.125f;
            }
        }
}

// ---------------------------------------------------- sparsemax (in-place rows)
__global__ __launch_bounds__(256)
void sparsemax_kernel(float* __restrict__ attn) {
    const int wave = threadIdx.x >> 6;
    const int lane = threadIdx.x & 63;
    const size_t row = (size_t)blockIdx.x * 4 + wave;
    float4* rp = (float4*)(attn + row * S_LEN);

    float z[32];
#pragma unroll
    for (int r = 0; r < 8; ++r) {
        float4 v = rp[r * 64 + lane];
        z[4 * r + 0] = v.x; z[4 * r + 1] = v.y;
        z[4 * r + 2] = v.z; z[4 * r + 3] = v.w;
    }
    float m = z[0];
#pragma unroll
    for (int j = 1; j < 32; ++j) m = fmaxf(m, z[j]);
    m = wave_max64(m);

    float lo = m - 1.0f, hi = m;
    for (int it = 0; it < 26; ++it) {
        const float mid = 0.5f * (lo + hi);
        float s = 0.0f;
#pragma unroll
        for (int j = 0; j < 32; ++j) s += fmaxf(z[j] - mid, 0.0f);
        s = wave_sum64(s);
        if (s >= 1.0f) lo = mid; else hi = mid;
    }
    const float tau0 = 0.5f * (lo + hi);

    float ssum = 0.0f, cnt = 0.0f;
#pragma unroll
    for (int j = 0; j < 32; ++j)
        if (z[j] > tau0) { ssum += z[j]; cnt += 1.0f; }
    ssum = wave_sum64(ssum);
    cnt  = wave_sum64(cnt);
    const float tau = (ssum - 1.0f) / cnt;

#pragma unroll
    for (int r = 0; r < 8; ++r) {
        float4 v;
        v.x = fmaxf(z[4 * r + 0] - tau, 0.0f);
        v.y = fmaxf(z[4 * r + 1] - tau, 0.0f);
        v.z = fmaxf(z[4 * r + 2] - tau, 0.0f);
        v.w = fmaxf(z[4 * r + 3] - tau, 0.0f);
        rp[r * 64 + lane] = v;
    }
}

// ------------------------------------------------- V [B,H,S,64] -> Vt [B,H,64,S]
__global__ __launch_bounds__(256)
void transpose_v(const unsigned short* __restrict__ V, unsigned short* __restrict__ Vt) {
    const int bh = blockIdx.y;
    const int s0 = blockIdx.x * 64;
    __shared__ unsigned short T[64 * 72];
    const int t = threadIdx.x;
#pragma unroll
    for (int i = 0; i < 2; ++i) {
        const int c = t + i * 256, r = c >> 3, q = (c & 7) * 8;
        *(uint4*)&T[r * 72 + q] = *(const uint4*)(V + ((size_t)bh * S_LEN + s0 + r) * 64 + q);
    }
    __syncthreads();
#pragma unroll
    for (int i = 0; i < 2; ++i) {
        const int c = t + i * 256, d = c >> 3, sq = (c & 7) * 8;
        unsigned short tmp[8] __attribute__((aligned(16)));
#pragma unroll
        for (int jj = 0; jj < 8; ++jj) tmp[jj] = T[(sq + jj) * 72 + d];
        *(uint4*)(Vt + ((size_t)bh * 64 + d) * S_LEN + s0 + sq) = *(uint4*)tmp;
    }
}

// ----------------------------------- attn_out = attn @ V (P fp32 -> bf16 in staging)
// Per (b,h): P[2048,2048] x V[2048,64]; output bf16 [B,S,DMODEL].
__global__ __launch_bounds__(256)
void pv_gemm(const float* __restrict__ attn, const unsigned short* __restrict__ Vt,
             unsigned short* __restrict__ AO_bf) {
    const int bh = blockIdx.z;
    const int b_ = bh >> 4, h = bh & 15;
    const float* P = attn + (size_t)bh * S_LEN * S_LEN;
    const unsigned short* Vh = Vt + (size_t)bh * HEAD_ELEMS;   // [64,2048]
    const int row0 = blockIdx.x * 128;

    __shared__ unsigned short Ps[128 * 72];
    __shared__ unsigned short Vs[64 * 72];

    const int t = threadIdx.x;
    const int w = t >> 6, lane = t & 63;
    const int l = lane & 15, quad = lane >> 4;

    f32x4 acc[2][4] = {};

    for (int k0 = 0; k0 < S_LEN; k0 += 64) {
        float4 pr[8]; uint4 vr[2];
#pragma unroll
        for (int i = 0; i < 8; ++i) {
            const int c = t + i * 256, r = c >> 4, q = (c & 15) * 4;
            pr[i] = *(const float4*)(P + (size_t)(row0 + r) * S_LEN + k0 + q);
        }
#pragma unroll
        for (int i = 0; i < 2; ++i) {
            const int c = t + i * 256, r = c >> 3, q = (c & 7) * 8;
            vr[i] = *(const uint4*)(Vh + (size_t)r * S_LEN + k0 + q);
        }
        __syncthreads();
#pragma unroll
        for (int i = 0; i < 8; ++i) {
            const int c = t + i * 256, r = c >> 4, q = (c & 15) * 4;
            unsigned int lo = ((unsigned)f2bf(pr[i].y) << 16) | f2bf(pr[i].x);
            unsigned int hi = ((unsigned)f2bf(pr[i].w) << 16) | f2bf(pr[i].z);
            uint2 st = { lo, hi };
            *(uint2*)&Ps[r * 72 + q] = st;
        }
#pragma unroll
        for (int i = 0; i < 2; ++i) {
            const int c = t + i * 256, r = c >> 3, q = (c & 7) * 8;
            *(uint4*)&Vs[r * 72 + q] = vr[i];
        }
        __syncthreads();
#pragma unroll
        for (int kk = 0; kk < 64; kk += 32) {
            bf16x8 a[2], b[4];
#pragma unroll
            for (int i = 0; i < 2; ++i)
                a[i] = *(const bf16x8*)&Ps[(w * 32 + i * 16 + l) * 72 + kk + quad * 8];
#pragma unroll
            for (int j = 0; j < 4; ++j)
                b[j] = *(const bf16x8*)&Vs[(j * 16 + l) * 72 + kk + quad * 8];
#pragma unroll
            for (int i = 0; i < 2; ++i)
#pragma unroll
                for (int j = 0; j < 4; ++j)
                    acc[i][j] = __builtin_amdgcn_mfma_f32_16x16x32_bf16(a[i], b[j], acc[i][j], 0, 0, 0);
        }
        __syncthreads();
    }

#pragma unroll
    for (int i = 0; i < 2; ++i)
#pragma unroll
        for (int r = 0; r < 4; ++r) {
            const int s = row0 + w * 32 + i * 16 + quad * 4 + r;
#pragma unroll
            for (int j = 0; j < 4; ++j) {
                const int d = j * 16 + l;
                AO_bf[((size_t)(b_ * S_LEN + s)) * DMODEL + h * 64 + d] = f2bf(acc[i][j][r]);
            }
        }
}

// ------------------------------------------- out = AO @ Wfc^T + bfc (bf16 MFMA)
__global__ __launch_bounds__(256)
void fc_gemm(const unsigned short* __restrict__ AO_bf,
             const unsigned short* __restrict__ Wfc_bf,
             const float* __restrict__ bfc, float* __restrict__ out) {
    const int row0 = blockIdx.x * 128;
    const int col0 = blockIdx.y * 128;

    __shared__ unsigned short As[128 * 40];
    __shared__ unsigned short Bs[128 * 40];

    const int t = threadIdx.x;
    const int wid = t >> 6, lane = t & 63;
    const int wm = wid >> 1, wn = wid & 1;
    const int l = lane & 15, quad = lane >> 4;

    f32x4 acc[4][4];
#pragma unroll
    for (int i = 0; i < 4; ++i)
#pragma unroll
        for (int j = 0; j < 4; ++j) {
            float b_ = bfc[col0 + wn * 64 + j * 16 + l];
            acc[i][j] = (f32x4){ b_, b_, b_, b_ };
        }

    for (int k0 = 0; k0 < DMODEL; k0 += 32) {
        uint4 ar[2], br[2];
#pragma unroll
        for (int i = 0; i < 2; ++i) {
            const int c = t + i * 256, r = c >> 2, q = (c & 3) * 8;
            ar[i] = *(const uint4*)(AO_bf + (size_t)(row0 + r) * DMODEL + k0 + q);
            br[i] = *(const uint4*)(Wfc_bf + (size_t)(col0 + r) * DMODEL + k0 + q);
        }
        __syncthreads();
#pragma unroll
        for (int i = 0; i < 2; ++i) {
            const int c = t + i * 256, r = c >> 2, q = (c & 3) * 8;
            *(uint4*)&As[r * 40 + q] = ar[i];
            *(uint4*)&Bs[r * 40 + q] = br[i];
        }
        __syncthreads();
        bf16x8 a[4], b[4];
#pragma unroll
        for (int i = 0; i < 4; ++i)
            a[i] = *(const bf16x8*)&As[(wm * 64 + i * 16 + l) * 40 + quad * 8];
#pragma unroll
        for (int j = 0; j < 4; ++j)
            b[j] = *(const bf16x8*)&Bs[(wn * 64 + j * 16 + l) * 40 + quad * 8];
#pragma unroll
        for (int i = 0; i < 4; ++i)
#pragma unroll
            for (int j = 0; j < 4; ++j)
                acc[i][j] = __builtin_amdgcn_mfma_f32_16x16x32_bf16(a[i], b[j], acc[i][j], 0, 0, 0);
    }

#pragma unroll
    for (int i = 0; i < 4; ++i)
#pragma unroll
        for (int r = 0; r < 4; ++r) {
            const int m = row0 + wm * 64 + i * 16 + quad * 4 + r;
#pragma unroll
            for (int j = 0; j < 4; ++j) {
                const int n = col0 + wn * 64 + j * 16 + l;
                out[(size_t)m * DMODEL + n] = acc[i][j][r];
            }
        }
}

// ----------------------------------------------------------------------- launch
extern "C" void kernel_launch(void* const* d_in, const int* in_sizes, int n_in,
                              void* d_out, int out_size, void* d_ws, size_t ws_size,
                              hipStream_t stream) {
    const float* q   = (const float*)d_in[0];
    const float* k   = (const float*)d_in[1];
    const float* v   = (const float*)d_in[2];
    const float* Wq  = (const float*)d_in[3];
    const float* bq  = (const float*)d_in[4];
    const float* Wk  = (const float*)d_in[5];
    const float* bk  = (const float*)d_in[6];
    const float* Wv  = (const float*)d_in[7];
    const float* bv  = (const float*)d_in[8];
    const float* Wfc = (const float*)d_in[9];
    const float* bfc = (const float*)d_in[10];

    float* out  = (float*)d_out;                       // [B,S,D] fp32
    float* attn = out + (size_t)M_ROWS * DMODEL;       // [B,H,S,S] fp32

    // workspace (bytes):
    //  [ 0,24M): x_bf (xq,xk,xv)   -- later: [0,8M)=AO_bf alias, [8M,16M)=Vt alias
    //  [24,32M): W_bf (Wq,Wk,Wv,Wfc)
    //  [32,40M): Q_bf   [40,48M): K_bf   [48,56M): V_bf
    char* ws = (char*)d_ws;
    unsigned short* x_bf = (unsigned short*)ws;
    unsigned short* W_bf = (unsigned short*)(ws + (24u << 20));
    unsigned short* Q_bf = (unsigned short*)(ws + (32u << 20));
    unsigned short* K_bf = (unsigned short*)(ws + (40u << 20));
    unsigned short* V_bf = (unsigned short*)(ws + (48u << 20));
    unsigned short* AO_bf = x_bf;                              // aliases xq_bf
    unsigned short* Vt_bf = x_bf + (4u << 20);                 // aliases xk_bf

    cast_kernel<<<16384, 256, 0, stream>>>(q, k, v, Wq, Wk, Wv, Wfc, x_bf);
    qkv_gemm<<<dim3(32, 8, 3), 256, 0, stream>>>(x_bf, W_bf, bq, bk, bv, Q_bf, K_bf, V_bf);
    transpose_v<<<dim3(32, 32), 256, 0, stream>>>(V_bf, Vt_bf);
    logits_gemm<<<dim3(16, 16, 32), 256, 0, stream>>>(Q_bf, K_bf, attn);
    sparsemax_kernel<<<16384, 256, 0, stream>>>(attn);
    pv_gemm<<<dim3(16, 1, 32), 256, 0, stream>>>(attn, Vt_bf, AO_bf);
    fc_gemm<<<dim3(32, 8), 256, 0, stream>>>(AO_bf, W_bf + (3u << 20), bfc, out);
}

// Round 3
// 993.022 us; speedup vs baseline: 1.9868x; 1.1532x over previous
//
#include <hip/hip_runtime.h>
#include <hip/hip_bf16.h>
#include <cstdint>

// MultiHeadAttention w/ sparsemax: B=2, S=2048, D=1024, H=16, DK=64
#define S_LEN  2048
#define DMODEL 1024
#define NHEAD  16
#define M_ROWS 4096                       // B*S
#define HEAD_ELEMS (2048u * 64u)          // per (b,h) Q/K/V elems

typedef __attribute__((ext_vector_type(8))) short bf16x8;   // MFMA A/B frag (8 bf16)
typedef __attribute__((ext_vector_type(4))) float f32x4;    // MFMA C/D frag

__device__ __forceinline__ unsigned short f2bf(float f) {
    __hip_bfloat16 h = __float2bfloat16(f);
    return __builtin_bit_cast(unsigned short, h);
}
__device__ __forceinline__ float bf2f(unsigned short u) {
    return __builtin_bit_cast(float, (unsigned)u << 16);
}

// ---------------------------------------------------------------- wave reduce
__device__ __forceinline__ float wave_sum64(float v) {
    v += __shfl_xor(v, 32, 64); v += __shfl_xor(v, 16, 64);
    v += __shfl_xor(v, 8, 64);  v += __shfl_xor(v, 4, 64);
    v += __shfl_xor(v, 2, 64);  v += __shfl_xor(v, 1, 64);
    return v;
}
__device__ __forceinline__ float wave_max64(float v) {
    v = fmaxf(v, __shfl_xor(v, 32, 64)); v = fmaxf(v, __shfl_xor(v, 16, 64));
    v = fmaxf(v, __shfl_xor(v, 8, 64));  v = fmaxf(v, __shfl_xor(v, 4, 64));
    v = fmaxf(v, __shfl_xor(v, 2, 64));  v = fmaxf(v, __shfl_xor(v, 1, 64));
    return v;
}
__device__ __forceinline__ int lanes_below(unsigned long long m) {
    return __builtin_amdgcn_mbcnt_hi((unsigned)(m >> 32),
           __builtin_amdgcn_mbcnt_lo((unsigned)m, 0));
}

// --------------------------------------------------------------- cast fp32->bf16
// 16M elems: [0,4M)=xq [4M,8M)=xk [8M,12M)=xv [12M,13M)=Wq [13M,14M)=Wk
// [14M,15M)=Wv [15M,16M)=Wfc. Output contiguous bf16 at ws+0.
__global__ __launch_bounds__(256)
void cast_kernel(const float* __restrict__ xq, const float* __restrict__ xk,
                 const float* __restrict__ xv, const float* __restrict__ Wq,
                 const float* __restrict__ Wk, const float* __restrict__ Wv,
                 const float* __restrict__ Wfc, unsigned short* __restrict__ out) {
    const size_t e = ((size_t)blockIdx.x * 256 + threadIdx.x) * 4;
    const size_t M1 = 1u << 20, M4 = 4u << 20;
    const float* src; size_t off;
    if      (e < M4)        { src = xq;  off = e; }
    else if (e < 2 * M4)    { src = xk;  off = e - M4; }
    else if (e < 3 * M4)    { src = xv;  off = e - 2 * M4; }
    else if (e < 13 * M1)   { src = Wq;  off = e - 3 * M4; }
    else if (e < 14 * M1)   { src = Wk;  off = e - 13 * M1; }
    else if (e < 15 * M1)   { src = Wv;  off = e - 14 * M1; }
    else                    { src = Wfc; off = e - 15 * M1; }
    float4 v = *(const float4*)(src + off);
    unsigned int lo = ((unsigned)f2bf(v.y) << 16) | f2bf(v.x);
    unsigned int hi = ((unsigned)f2bf(v.w) << 16) | f2bf(v.z);
    uint2 st = { lo, hi };
    *(uint2*)(out + e) = st;
}

// ------------------------------------------------- qkv: C = A@W^T + b (bf16 MFMA)
// A[4096,1024] bf16, W[1024,1024] bf16 (NT). Output head-major bf16 [B,H,S,64].
__global__ __launch_bounds__(256)
void qkv_gemm(const unsigned short* __restrict__ x_bf,
              const unsigned short* __restrict__ W_bf,
              const float* __restrict__ bq, const float* __restrict__ bk,
              const float* __restrict__ bv,
              unsigned short* __restrict__ Q_bf, unsigned short* __restrict__ K_bf,
              unsigned short* __restrict__ V_bf) {
    const int which = blockIdx.z;
    const unsigned short* A = x_bf + (size_t)which * (4u << 20);
    const unsigned short* W = W_bf + (size_t)which * (1u << 20);
    const float* bias = (which == 0) ? bq : (which == 1) ? bk : bv;
    unsigned short* dst = (which == 0) ? Q_bf : (which == 1) ? K_bf : V_bf;

    const int row0 = blockIdx.x * 128;
    const int col0 = blockIdx.y * 128;

    __shared__ unsigned short As[128 * 40];   // stride 40 bf16 = 80 B (2-way free)
    __shared__ unsigned short Bs[128 * 40];

    const int t = threadIdx.x;
    const int wid = t >> 6, lane = t & 63;
    const int wm = wid >> 1, wn = wid & 1;
    const int l = lane & 15, quad = lane >> 4;

    f32x4 acc[4][4];
#pragma unroll
    for (int i = 0; i < 4; ++i)
#pragma unroll
        for (int j = 0; j < 4; ++j) {
            float b_ = bias[col0 + wn * 64 + j * 16 + l];
            acc[i][j] = (f32x4){ b_, b_, b_, b_ };
        }

    for (int k0 = 0; k0 < DMODEL; k0 += 32) {
        uint4 ar[2], br[2];
#pragma unroll
        for (int i = 0; i < 2; ++i) {
            const int c = t + i * 256, r = c >> 2, q = (c & 3) * 8;
            ar[i] = *(const uint4*)(A + (size_t)(row0 + r) * DMODEL + k0 + q);
            br[i] = *(const uint4*)(W + (size_t)(col0 + r) * DMODEL + k0 + q);
        }
        __syncthreads();
#pragma unroll
        for (int i = 0; i < 2; ++i) {
            const int c = t + i * 256, r = c >> 2, q = (c & 3) * 8;
            *(uint4*)&As[r * 40 + q] = ar[i];
            *(uint4*)&Bs[r * 40 + q] = br[i];
        }
        __syncthreads();
        bf16x8 a[4], b[4];
#pragma unroll
        for (int i = 0; i < 4; ++i)
            a[i] = *(const bf16x8*)&As[(wm * 64 + i * 16 + l) * 40 + quad * 8];
#pragma unroll
        for (int j = 0; j < 4; ++j)
            b[j] = *(const bf16x8*)&Bs[(wn * 64 + j * 16 + l) * 40 + quad * 8];
#pragma unroll
        for (int i = 0; i < 4; ++i)
#pragma unroll
            for (int j = 0; j < 4; ++j)
                acc[i][j] = __builtin_amdgcn_mfma_f32_16x16x32_bf16(a[i], b[j], acc[i][j], 0, 0, 0);
    }

    // scatter bf16 to [B,H,S,64]
#pragma unroll
    for (int i = 0; i < 4; ++i)
#pragma unroll
        for (int r = 0; r < 4; ++r) {
            const int m = row0 + wm * 64 + i * 16 + quad * 4 + r;
            const int b_ = m >> 11, s = m & 2047;
#pragma unroll
            for (int j = 0; j < 4; ++j) {
                const int n = col0 + wn * 64 + j * 16 + l;
                const int h = n >> 6, d = n & 63;
                dst[(((size_t)(b_ * NHEAD + h)) * S_LEN + s) * 64 + d] = f2bf(acc[i][j][r]);
            }
        }
}

// --------------------------------------------- logits = Q@K^T / 8 (bf16 MFMA, K=64)
__global__ __launch_bounds__(256)
void logits_gemm(const unsigned short* __restrict__ Q_bf,
                 const unsigned short* __restrict__ K_bf,
                 float* __restrict__ attn) {
    const int bh = blockIdx.z;
    const unsigned short* Qh = Q_bf + (size_t)bh * HEAD_ELEMS;
    const unsigned short* Kh = K_bf + (size_t)bh * HEAD_ELEMS;
    const int row0 = blockIdx.x * 128;
    const int col0 = blockIdx.y * 128;

    __shared__ unsigned short As[128 * 72];   // stride 72 bf16 = 144 B
    __shared__ unsigned short Bs[128 * 72];

    const int t = threadIdx.x;
    const int wid = t >> 6, lane = t & 63;
    const int wm = wid >> 1, wn = wid & 1;
    const int l = lane & 15, quad = lane >> 4;

#pragma unroll
    for (int i = 0; i < 4; ++i) {
        const int c = t + i * 256, r = c >> 3, q = (c & 7) * 8;
        *(uint4*)&As[r * 72 + q] = *(const uint4*)(Qh + (size_t)(row0 + r) * 64 + q);
        *(uint4*)&Bs[r * 72 + q] = *(const uint4*)(Kh + (size_t)(col0 + r) * 64 + q);
    }
    __syncthreads();

    f32x4 acc[4][4] = {};
#pragma unroll
    for (int kk = 0; kk < 64; kk += 32) {
        bf16x8 a[4], b[4];
#pragma unroll
        for (int i = 0; i < 4; ++i)
            a[i] = *(const bf16x8*)&As[(wm * 64 + i * 16 + l) * 72 + kk + quad * 8];
#pragma unroll
        for (int j = 0; j < 4; ++j)
            b[j] = *(const bf16x8*)&Bs[(wn * 64 + j * 16 + l) * 72 + kk + quad * 8];
#pragma unroll
        for (int i = 0; i < 4; ++i)
#pragma unroll
            for (int j = 0; j < 4; ++j)
                acc[i][j] = __builtin_amdgcn_mfma_f32_16x16x32_bf16(a[i], b[j], acc[i][j], 0, 0, 0);
    }

    float* ap = attn + (size_t)bh * S_LEN * S_LEN;
#pragma unroll
    for (int i = 0; i < 4; ++i)
#pragma unroll
        for (int r = 0; r < 4; ++r) {
            const int m = row0 + wm * 64 + i * 16 + quad * 4 + r;
#pragma unroll
            for (int j = 0; j < 4; ++j) {
                const int n = col0 + wn * 64 + j * 16 + l;
                ap[(size_t)m * S_LEN + n] = acc[i][j][r] * 0.125f;
            }
        }
}

// ---------------------------------------- fused sparsemax + P@V (per-row wave)
// In-place S -> P on attn rows; PV via sparse compaction (support << 2048).
// grid 16384 x 256; one wave per attention row.
__global__ __launch_bounds__(256)
void smpv_kernel(float* __restrict__ attn, const unsigned short* __restrict__ V_bf,
                 unsigned short* __restrict__ AO_bf) {
    const int wave = threadIdx.x >> 6;
    const int lane = threadIdx.x & 63;
    const size_t row = (size_t)blockIdx.x * 4 + wave;   // [0, 65536)
    const int bh = (int)(row >> 11), s = (int)(row & 2047);
    const int b_ = bh >> 4, h = bh & 15;
    float4* rp = (float4*)(attn + row * S_LEN);
    const unsigned short* Vh = V_bf + (size_t)bh * HEAD_ELEMS;  // [2048,64]

    __shared__ uint2 list[4][512];   // per-wave (col, p) compaction buffer

    // ---- load row: z[4r+j] lives at col r*256 + lane*4 + j
    float z[32];
#pragma unroll
    for (int r = 0; r < 8; ++r) {
        float4 v = rp[r * 64 + lane];
        z[4 * r + 0] = v.x; z[4 * r + 1] = v.y;
        z[4 * r + 2] = v.z; z[4 * r + 3] = v.w;
    }
    float m = z[0];
#pragma unroll
    for (int j = 1; j < 32; ++j) m = fmaxf(m, z[j]);
    m = wave_max64(m);

    // ---- bisection for tau0 (support set resolver; 18 iters -> 4e-6 bracket)
    float lo = m - 1.0f, hi = m;
    for (int it = 0; it < 18; ++it) {
        const float mid = 0.5f * (lo + hi);
        float sacc = 0.0f;
#pragma unroll
        for (int j = 0; j < 32; ++j) sacc += fmaxf(z[j] - mid, 0.0f);
        sacc = wave_sum64(sacc);
        if (sacc >= 1.0f) lo = mid; else hi = mid;   // uniform -> no divergence
    }
    const float tau0 = 0.5f * (lo + hi);

    // ---- exact refine on the resolved support
    float ssum = 0.0f, cnt = 0.0f;
#pragma unroll
    for (int j = 0; j < 32; ++j)
        if (z[j] > tau0) { ssum += z[j]; cnt += 1.0f; }
    ssum = wave_sum64(ssum);
    cnt  = wave_sum64(cnt);
    const float tau = (ssum - 1.0f) / cnt;

    // ---- P = relu(z - tau): write back in place (required output)
#pragma unroll
    for (int j = 0; j < 32; ++j) z[j] = fmaxf(z[j] - tau, 0.0f);
#pragma unroll
    for (int r = 0; r < 8; ++r) {
        float4 v = { z[4 * r + 0], z[4 * r + 1], z[4 * r + 2], z[4 * r + 3] };
        rp[r * 64 + lane] = v;
    }

    // ---- PV: out[d=lane] = sum_k p_k * V[k][d], via per-round compaction
    float acc = 0.0f;
#pragma unroll 1
    for (int rr = 0; rr < 4; ++rr) {               // rounds of 8 elems/lane
        int base = 0;
#pragma unroll
        for (int e = 0; e < 8; ++e) {
            const int r = rr * 2 + (e >> 2), jj = e & 3;
            const float pv = z[4 * r + jj];
            const unsigned long long mk = __ballot(pv > 0.0f);
            if (pv > 0.0f) {
                const int pos = base + lanes_below(mk);
                uint2 kp = { (unsigned)(r * 256 + lane * 4 + jj),
                             __builtin_bit_cast(unsigned, pv) };
                list[wave][pos] = kp;
            }
            base += __popcll(mk);
        }
        __threadfence_block();                     // LDS writes -> reads (in-wave)
        const int total = base;
        int i = 0;
        for (; i + 2 <= total; i += 2) {
            uint2 kp0 = list[wave][i], kp1 = list[wave][i + 1];
            float v0 = bf2f(Vh[(size_t)kp0.x * 64 + lane]);
            float v1 = bf2f(Vh[(size_t)kp1.x * 64 + lane]);
            acc += __builtin_bit_cast(float, kp0.y) * v0;
            acc += __builtin_bit_cast(float, kp1.y) * v1;
        }
        if (i < total) {
            uint2 kp0 = list[wave][i];
            acc += __builtin_bit_cast(float, kp0.y) * bf2f(Vh[(size_t)kp0.x * 64 + lane]);
        }
        __threadfence_block();                     // reads done before next round's writes
    }

    AO_bf[((size_t)(b_ * S_LEN + s)) * DMODEL + h * 64 + lane] = f2bf(acc);
}

// ------------------------------------------- out = AO @ Wfc^T + bfc (bf16 MFMA)
__global__ __launch_bounds__(256)
void fc_gemm(const unsigned short* __restrict__ AO_bf,
             const unsigned short* __restrict__ Wfc_bf,
             const float* __restrict__ bfc, float* __restrict__ out) {
    const int row0 = blockIdx.x * 128;
    const int col0 = blockIdx.y * 128;

    __shared__ unsigned short As[128 * 40];
    __shared__ unsigned short Bs[128 * 40];

    const int t = threadIdx.x;
    const int wid = t >> 6, lane = t & 63;
    const int wm = wid >> 1, wn = wid & 1;
    const int l = lane & 15, quad = lane >> 4;

    f32x4 acc[4][4];
#pragma unroll
    for (int i = 0; i < 4; ++i)
#pragma unroll
        for (int j = 0; j < 4; ++j) {
            float b_ = bfc[col0 + wn * 64 + j * 16 + l];
            acc[i][j] = (f32x4){ b_, b_, b_, b_ };
        }

    for (int k0 = 0; k0 < DMODEL; k0 += 32) {
        uint4 ar[2], br[2];
#pragma unroll
        for (int i = 0; i < 2; ++i) {
            const int c = t + i * 256, r = c >> 2, q = (c & 3) * 8;
            ar[i] = *(const uint4*)(AO_bf + (size_t)(row0 + r) * DMODEL + k0 + q);
            br[i] = *(const uint4*)(Wfc_bf + (size_t)(col0 + r) * DMODEL + k0 + q);
        }
        __syncthreads();
#pragma unroll
        for (int i = 0; i < 2; ++i) {
            const int c = t + i * 256, r = c >> 2, q = (c & 3) * 8;
            *(uint4*)&As[r * 40 + q] = ar[i];
            *(uint4*)&Bs[r * 40 + q] = br[i];
        }
        __syncthreads();
        bf16x8 a[4], b[4];
#pragma unroll
        for (int i = 0; i < 4; ++i)
            a[i] = *(const bf16x8*)&As[(wm * 64 + i * 16 + l) * 40 + quad * 8];
#pragma unroll
        for (int j = 0; j < 4; ++j)
            b[j] = *(const bf16x8*)&Bs[(wn * 64 + j * 16 + l) * 40 + quad * 8];
#pragma unroll
        for (int i = 0; i < 4; ++i)
#pragma unroll
            for (int j = 0; j < 4; ++j)
                acc[i][j] = __builtin_amdgcn_mfma_f32_16x16x32_bf16(a[i], b[j], acc[i][j], 0, 0, 0);
    }

#pragma unroll
    for (int i = 0; i < 4; ++i)
#pragma unroll
        for (int r = 0; r < 4; ++r) {
            const int m = row0 + wm * 64 + i * 16 + quad * 4 + r;
#pragma unroll
            for (int j = 0; j < 4; ++j) {
                const int n = col0 + wn * 64 + j * 16 + l;
                out[(size_t)m * DMODEL + n] = acc[i][j][r];
            }
        }
}

// ----------------------------------------------------------------------- launch
extern "C" void kernel_launch(void* const* d_in, const int* in_sizes, int n_in,
                              void* d_out, int out_size, void* d_ws, size_t ws_size,
                              hipStream_t stream) {
    const float* q   = (const float*)d_in[0];
    const float* k   = (const float*)d_in[1];
    const float* v   = (const float*)d_in[2];
    const float* Wq  = (const float*)d_in[3];
    const float* bq  = (const float*)d_in[4];
    const float* Wk  = (const float*)d_in[5];
    const float* bk  = (const float*)d_in[6];
    const float* Wv  = (const float*)d_in[7];
    const float* bv  = (const float*)d_in[8];
    const float* Wfc = (const float*)d_in[9];
    const float* bfc = (const float*)d_in[10];

    float* out  = (float*)d_out;                       // [B,S,D] fp32
    float* attn = out + (size_t)M_ROWS * DMODEL;       // [B,H,S,S] fp32

    // workspace (bytes):
    //  [ 0,24M): x_bf (xq,xk,xv)   -- later: [0,8M)=AO_bf alias (qkv reads done)
    //  [24,32M): W_bf (Wq,Wk,Wv,Wfc)
    //  [32,40M): Q_bf   [40,48M): K_bf   [48,56M): V_bf
    char* ws = (char*)d_ws;
    unsigned short* x_bf = (unsigned short*)ws;
    unsigned short* W_bf = (unsigned short*)(ws + (24u << 20));
    unsigned short* Q_bf = (unsigned short*)(ws + (32u << 20));
    unsigned short* K_bf = (unsigned short*)(ws + (40u << 20));
    unsigned short* V_bf = (unsigned short*)(ws + (48u << 20));
    unsigned short* AO_bf = x_bf;                      // aliases xq_bf (safe: qkv done)

    cast_kernel<<<16384, 256, 0, stream>>>(q, k, v, Wq, Wk, Wv, Wfc, x_bf);
    qkv_gemm<<<dim3(32, 8, 3), 256, 0, stream>>>(x_bf, W_bf, bq, bk, bv, Q_bf, K_bf, V_bf);
    logits_gemm<<<dim3(16, 16, 32), 256, 0, stream>>>(Q_bf, K_bf, attn);
    smpv_kernel<<<16384, 256, 0, stream>>>(attn, V_bf, AO_bf);
    fc_gemm<<<dim3(32, 8), 256, 0, stream>>>(AO_bf, W_bf + (3u << 20), bfc, out);
}